// Round 1
// baseline (667.393 us; speedup 1.0000x reference)
//
#include <hip/hip_runtime.h>
#include <hip/hip_bf16.h>

// GCN 2-layer forward: N=100000 nodes, E=3.2M edges, F_IN=256, HIDDEN=16, C=10.
// All f32. Edge dtype (int32 vs int64) detected on-device.

#define F_IN 256
#define HID 16
#define NCLS 10

__device__ __forceinline__ int eload(const void* ei, long long idx, int is64) {
  if (is64) return (int)((const long long*)ei)[idx];
  return ((const int*)ei)[idx];
}

// Detect whether edge_index is int64 or int32. If the data is int32, reading
// pairs as int64 yields values with a (almost surely) nonzero high word >= N.
__global__ void k_detect(const void* ei, int N, int* flag) {
  if (blockIdx.x == 0 && threadIdx.x == 0) {
    const unsigned long long* p = (const unsigned long long*)ei;
    int is64 = 1;
    for (int i = 0; i < 16; ++i) {
      if (p[i] >= (unsigned long long)N) { is64 = 0; break; }
    }
    *flag = is64;
  }
}

__global__ void k_deg(const void* ei, long long E, const int* flag,
                      float* __restrict__ deg) {
  int is64 = *flag;
  long long stride = (long long)gridDim.x * blockDim.x;
  for (long long i = (long long)blockIdx.x * blockDim.x + threadIdx.x; i < E;
       i += stride) {
    int v = eload(ei, E + i, is64);  // col
    atomicAdd(&deg[v], 1.0f);
  }
}

__global__ void k_rsqrt(float* deg, int N) {
  int i = blockIdx.x * blockDim.x + threadIdx.x;
  if (i < N) deg[i] = rsqrtf(deg[i] + 1.0f);  // +1 self-loop; always > 0
}

// h1 = x @ W1   [N,256] x [256,16]
__global__ __launch_bounds__(256) void k_gemm1(const float* __restrict__ x,
                                               const float* __restrict__ W1,
                                               float* __restrict__ h1, int N) {
  __shared__ float xs[32][F_IN + 1];   // +1 pad: conflict-free column reads
  __shared__ float wl[F_IN * HID];     // 16 KB
  const int tid = threadIdx.x;
  for (int t = tid; t < F_IN * HID; t += 256) wl[t] = W1[t];
  const int nb = blockIdx.x * 32;
  const float4* x4 = (const float4*)(x + (long long)nb * F_IN);
  for (int t = tid; t < 32 * (F_IN / 4); t += 256) {
    int r = t >> 6, c4 = t & 63;
    if (nb + r < N) {
      float4 v = x4[t];
      xs[r][c4 * 4 + 0] = v.x;
      xs[r][c4 * 4 + 1] = v.y;
      xs[r][c4 * 4 + 2] = v.z;
      xs[r][c4 * 4 + 3] = v.w;
    }
  }
  __syncthreads();
  const int n = tid & 31;
  const int j0 = (tid >> 5) * 2;  // 8 groups x 2 outputs = 16
  float a0 = 0.f, a1 = 0.f;
#pragma unroll 8
  for (int k = 0; k < F_IN; ++k) {
    float xv = xs[n][k];
    a0 = fmaf(xv, wl[k * HID + j0], a0);
    a1 = fmaf(xv, wl[k * HID + j0 + 1], a1);
  }
  int node = nb + n;
  if (node < N) {
    h1[(long long)node * HID + j0] = a0;
    h1[(long long)node * HID + j0 + 1] = a1;
  }
}

// agg1[v] += h1[u] * dis[u]*dis[v]  over edges; thread per (edge, feature)
__global__ void k_scatter1(const void* ei, long long E, const int* flag,
                           const float* __restrict__ h1,
                           const float* __restrict__ dis,
                           float* __restrict__ agg1) {
  int is64 = *flag;
  int total = (int)(E * HID);
  int stride = gridDim.x * blockDim.x;
  for (int i = blockIdx.x * blockDim.x + threadIdx.x; i < total; i += stride) {
    int e = i >> 4;
    int j = i & 15;
    int u = eload(ei, e, is64);
    int v = eload(ei, E + e, is64);
    float norm = dis[u] * dis[v];
    atomicAdd(&agg1[(long long)v * HID + j], h1[(long long)u * HID + j] * norm);
  }
}

// out1 = relu(agg1 + h1*d^2 + b1); h2 = out1 @ W2  (fused)
__global__ __launch_bounds__(256) void k_fin1gemm2(
    const float* __restrict__ agg1, const float* __restrict__ h1,
    const float* __restrict__ dis, const float* __restrict__ b1,
    const float* __restrict__ W2, float* __restrict__ h2, int N) {
  __shared__ float w2s[HID * NCLS];
  __shared__ float b1s[HID];
  if (threadIdx.x < HID * NCLS) w2s[threadIdx.x] = W2[threadIdx.x];
  if (threadIdx.x < HID) b1s[threadIdx.x] = b1[threadIdx.x];
  __syncthreads();
  int v = blockIdx.x * blockDim.x + threadIdx.x;
  if (v >= N) return;
  float d = dis[v];
  float d2 = d * d;
  float a[HID];
  const float4* ag = (const float4*)(agg1 + (long long)v * HID);
  const float4* hh = (const float4*)(h1 + (long long)v * HID);
#pragma unroll
  for (int q = 0; q < 4; ++q) {
    float4 av = ag[q], hv = hh[q];
    float t0 = av.x + hv.x * d2 + b1s[q * 4 + 0];
    float t1 = av.y + hv.y * d2 + b1s[q * 4 + 1];
    float t2 = av.z + hv.z * d2 + b1s[q * 4 + 2];
    float t3 = av.w + hv.w * d2 + b1s[q * 4 + 3];
    a[q * 4 + 0] = t0 > 0.f ? t0 : 0.f;
    a[q * 4 + 1] = t1 > 0.f ? t1 : 0.f;
    a[q * 4 + 2] = t2 > 0.f ? t2 : 0.f;
    a[q * 4 + 3] = t3 > 0.f ? t3 : 0.f;
  }
#pragma unroll
  for (int jj = 0; jj < NCLS; ++jj) {
    float s = 0.f;
#pragma unroll
    for (int j = 0; j < HID; ++j) s = fmaf(a[j], w2s[j * NCLS + jj], s);
    h2[(long long)v * NCLS + jj] = s;
  }
}

__global__ void k_scatter2(const void* ei, long long E, const int* flag,
                           const float* __restrict__ h2,
                           const float* __restrict__ dis,
                           float* __restrict__ agg2) {
  int is64 = *flag;
  int total = (int)(E * NCLS);
  int stride = gridDim.x * blockDim.x;
  for (int i = blockIdx.x * blockDim.x + threadIdx.x; i < total; i += stride) {
    int e = i / NCLS;           // compiler magic-div
    int j = i - e * NCLS;
    int u = eload(ei, e, is64);
    int v = eload(ei, E + e, is64);
    float norm = dis[u] * dis[v];
    atomicAdd(&agg2[(long long)v * NCLS + j],
              h2[(long long)u * NCLS + j] * norm);
  }
}

// logits = agg2 + h2*d^2 + b2; out = log_softmax(logits)
__global__ void k_fin2(const float* __restrict__ agg2,
                       const float* __restrict__ h2,
                       const float* __restrict__ dis,
                       const float* __restrict__ b2, float* __restrict__ out,
                       int N) {
  int v = blockIdx.x * blockDim.x + threadIdx.x;
  if (v >= N) return;
  float d = dis[v];
  float d2 = d * d;
  float vals[NCLS];
  float m = -1e30f;
#pragma unroll
  for (int j = 0; j < NCLS; ++j) {
    float t = agg2[(long long)v * NCLS + j] + h2[(long long)v * NCLS + j] * d2 +
              b2[j];
    vals[j] = t;
    m = fmaxf(m, t);
  }
  float s = 0.f;
#pragma unroll
  for (int j = 0; j < NCLS; ++j) s += expf(vals[j] - m);
  float ls = logf(s);
#pragma unroll
  for (int j = 0; j < NCLS; ++j)
    out[(long long)v * NCLS + j] = vals[j] - m - ls;
}

static inline long long llmin(long long a, long long b) { return a < b ? a : b; }

extern "C" void kernel_launch(void* const* d_in, const int* in_sizes, int n_in,
                              void* d_out, int out_size, void* d_ws,
                              size_t ws_size, hipStream_t stream) {
  const float* x = (const float*)d_in[0];
  const void* ei = d_in[1];
  const float* W1 = (const float*)d_in[2];
  const float* b1 = (const float*)d_in[3];
  const float* W2 = (const float*)d_in[4];
  const float* b2 = (const float*)d_in[5];
  float* out = (float*)d_out;

  const int N = in_sizes[0] / F_IN;       // 100000
  const long long E = in_sizes[1] / 2;    // 3200000

  // ws layout (floats): [16: flag+pad][deg/dis: N][agg1: 16N][agg2: 10N]
  //                     [h1: 16N][h2: 10N]   total (16 + 53N)*4 ≈ 21.2 MB
  int* flag = (int*)d_ws;
  float* base = (float*)d_ws;
  float* deg = base + 16;
  float* agg1 = deg + N;
  float* agg2 = agg1 + (long long)HID * N;
  float* h1 = agg2 + (long long)NCLS * N;
  float* h2 = h1 + (long long)HID * N;

  // zero flag + deg + agg1 + agg2 in one shot
  hipMemsetAsync(d_ws, 0, (size_t)(16 + (1 + HID + NCLS) * (long long)N) * 4,
                 stream);
  k_detect<<<1, 64, 0, stream>>>(ei, N, flag);

  int egrid = (int)llmin((E + 255) / 256, 8192);
  k_deg<<<egrid, 256, 0, stream>>>(ei, E, flag, deg);
  k_rsqrt<<<(N + 255) / 256, 256, 0, stream>>>(deg, N);

  k_gemm1<<<(N + 31) / 32, 256, 0, stream>>>(x, W1, h1, N);

  int s1grid = (int)llmin((E * HID + 255) / 256, 8192);
  k_scatter1<<<s1grid, 256, 0, stream>>>(ei, E, flag, h1, deg, agg1);

  k_fin1gemm2<<<(N + 255) / 256, 256, 0, stream>>>(agg1, h1, deg, b1, W2, h2,
                                                   N);

  int s2grid = (int)llmin((E * NCLS + 255) / 256, 8192);
  k_scatter2<<<s2grid, 256, 0, stream>>>(ei, E, flag, h2, deg, agg2);

  k_fin2<<<(N + 255) / 256, 256, 0, stream>>>(agg2, h2, deg, b2, out, N);
}